// Round 16
// baseline (368.508 us; speedup 1.0000x reference)
//
#include <hip/hip_runtime.h>
#include <math.h>

#define HH 180
#define WW 240
#define T_AGGC 3
#define NBC 4
#define BBC (NBC * T_AGGC)          // 12
#define M_EVC 32
#define ROWS (BBC * 2 * HH * WW)    // 1,036,800
#define MLPH 20
#define RNNH 20
#define LRELU_SLOPE 0.1f
#define HPAD 21
#define TBL 8192                    // table entries over t in [-1,1]
#define TE 64                       // table entries per block (build kernel)

__device__ __forceinline__ float lrelu(float x) { return x > 0.0f ? x : LRELU_SLOPE * x; }
__device__ __forceinline__ float sigm(float x)  { return 1.0f / (1.0f + __expf(-x)); }
__device__ __forceinline__ float ftanh(float x) { return 1.0f - 2.0f / (__expf(2.0f * x) + 1.0f); }

// fused {mlp, g} table lookup: returns lerped float2
__device__ __forceinline__ float2 tbl2_lerp(const float2* __restrict__ tbl, float t) {
    float x = (t + 1.0f) * (0.5f * (TBL - 1));
    x = fminf(fmaxf(x, 0.0f), (float)(TBL - 1));
    int idx = (int)x; if (idx > TBL - 2) idx = TBL - 2;
    float frac = x - (float)idx;
    float2 a = tbl[idx], b = tbl[idx + 1];
    return make_float2(fmaf(frac, b.x - a.x, a.x), fmaf(frac, b.y - a.y, a.y));
}

// ---------------- Table builder (4 threads/entry) + fused zeroing ----------------
__global__ __launch_bounds__(256) void build_tables(
    const float* __restrict__ W1, const float* __restrict__ b1,
    const float* __restrict__ W2, const float* __restrict__ b2,
    const float* __restrict__ W3, const float* __restrict__ b3,
    const float* __restrict__ rW1, const float* __restrict__ rb1,
    const float* __restrict__ Wih, const float* __restrict__ Whh,
    const float* __restrict__ bih, const float* __restrict__ bhh,
    const float* __restrict__ rW2, const float* __restrict__ rb2,
    float2* __restrict__ tbl2,
    unsigned int* __restrict__ mask_z, float* __restrict__ out_z,
    unsigned int* __restrict__ counters)   // [0]=wl_count, [1]=finish_count
{
    int tid = threadIdx.x;
    for (int gidx = blockIdx.x * blockDim.x + tid; gidx < ROWS / 4; gidx += gridDim.x * blockDim.x) {
        uint4 z = make_uint4(0u, 0u, 0u, 0u);
        ((uint4*)mask_z)[gidx] = z;
        ((uint4*)out_z)[gidx]  = z;
    }
    if (blockIdx.x == 0 && tid == 0) { counters[0] = 0u; counters[1] = 0u; }
    if (blockIdx.x * TE >= TBL) return;

    __shared__ __align__(16) float sW2m[MLPH * MLPH];
    __shared__ float sW1m[MLPH], sb1m[MLPH], sb2m[MLPH], sW3m[MLPH];
    __shared__ __align__(16) float sW[4 * RNNH * RNNH];   // Whh row-major
    __shared__ __align__(16) float sA[4 * RNNH], sC[4 * RNNH];
    __shared__ float sW2r[RNNH];
    __shared__ float sConst[2];                           // [0]=b3, [1]=rb2
    __shared__ float sH0[TE][HPAD];
    __shared__ float sRed[TE][4];

    for (int i = tid; i < MLPH * MLPH; i += blockDim.x) sW2m[i] = W2[i];
    for (int i = tid; i < 4 * RNNH * RNNH; i += blockDim.x) sW[i] = Whh[i];
    if (tid < MLPH) { sW1m[tid] = W1[tid]; sb1m[tid] = b1[tid]; sb2m[tid] = b2[tid]; sW3m[tid] = W3[tid]; }
    if (tid < 4 * RNNH) {
        float a = 0.0f, cc = bih[tid] + bhh[tid];
        for (int k = 0; k < RNNH; k++) {
            float w = Wih[tid * RNNH + k];
            a = fmaf(rW1[k], w, a);
            cc = fmaf(rb1[k], w, cc);
        }
        sA[tid] = a; sC[tid] = cc;
    }
    if (tid < RNNH) sW2r[tid] = rW2[tid];
    if (tid == 0) { sConst[0] = b3[0]; sConst[1] = rb2[0]; }
    __syncthreads();

    int e    = tid & (TE - 1);
    int part = tid >> 6;
    int ubase = part * 5;
    int i = blockIdx.x * TE + e;
    float t = -1.0f + (2.0f / (TBL - 1)) * (float)i;

    float h1[MLPH];
#pragma unroll
    for (int k = 0; k < MLPH; k++) h1[k] = lrelu(fmaf(t, sW1m[k], sb1m[k]));

    float vpart = 0.0f;
#pragma unroll
    for (int r = 0; r < 5; r++) {
        int j = ubase + r;
        float a = sb2m[j];
        const float* wr = &sW2m[j * MLPH];
#pragma unroll
        for (int k = 0; k < MLPH; k++) a = fmaf(h1[k], wr[k], a);
        vpart = fmaf(lrelu(a), sW3m[j], vpart);
    }
    sRed[e][part] = vpart;
    __syncthreads();
    float val = sRed[e][0] + sRed[e][1] + sRed[e][2] + sRed[e][3] + sConst[0];

    float c1loc[5];
#pragma unroll
    for (int r = 0; r < 5; r++) {
        int u = ubase + r;
        float gi = fmaf(val, sA[u],            sC[u]);
        float gg = fmaf(val, sA[u + 2 * RNNH], sC[u + 2 * RNNH]);
        float go = fmaf(val, sA[u + 3 * RNNH], sC[u + 3 * RNNH]);
        float cn = sigm(gi) * ftanh(gg);
        c1loc[r] = cn;
        sH0[e][u] = sigm(go) * ftanh(cn);
    }
    __syncthreads();

    float opart = 0.0f;
#pragma unroll
    for (int r = 0; r < 5; r++) {
        int u = ubase + r;
        float gi = sC[u], gf = sC[u + RNNH], gg = sC[u + 2 * RNNH], go = sC[u + 3 * RNNH];
        const float* wi = &sW[u * RNNH];
        const float* wf = &sW[(u + RNNH) * RNNH];
        const float* wg = &sW[(u + 2 * RNNH) * RNNH];
        const float* wo = &sW[(u + 3 * RNNH) * RNNH];
#pragma unroll
        for (int k = 0; k < RNNH; k++) {
            float hk = sH0[e][k];
            gi = fmaf(hk, wi[k], gi);
            gf = fmaf(hk, wf[k], gf);
            gg = fmaf(hk, wg[k], gg);
            go = fmaf(hk, wo[k], go);
        }
        float c2 = fmaf(sigm(gf), c1loc[r], sigm(gi) * ftanh(gg));
        opart = fmaf(sigm(go) * ftanh(c2), sW2r[u], opart);
    }
    __syncthreads();
    sRed[e][part] = opart;
    __syncthreads();
    if (part == 0)
        tbl2[i] = make_float2(val, sRed[e][0] + sRed[e][1] + sRed[e][2] + sRed[e][3] + sConst[1]);
}

// ---------------- shared LSTM fallback body ----------------
__device__ void lstm_row(
    int row, unsigned m,
    const float* __restrict__ vox, const float2* __restrict__ vv,
    const float (*sW1t)[2 * RNNH], const float (*sW2t)[2 * RNNH],
    const float* sA, const float* sC, const float* sW2r, float sb2o,
    float* myh, float* __restrict__ out)
{
    const float* vrow = vox + (size_t)row * M_EVC;
    float2 v2 = vv[row];

    float s = 0.0f;
    {
        unsigned mm = m;
        while (mm) {
            int j = __ffs(mm) - 1; mm &= mm - 1;
            float v;
            if (j == 0)       v = v2.x;
            else if (j == 16) v = v2.y;
            else              v = vrow[j];
            s += v;
        }
    }
    if (s == 0.0f) { out[row] = 0.0f; return; }

    int len = __popc(m);
    float c[RNNH];
    float oacc;

    {
        float x0 = (m & 1u) ? v2.x : 0.0f;
        oacc = sb2o;
#pragma unroll
        for (int u = 0; u < RNNH; u++) {
            float gi = fmaf(x0, sA[u],            sC[u]);
            float gg = fmaf(x0, sA[u + 2 * RNNH], sC[u + 2 * RNNH]);
            float go = fmaf(x0, sA[u + 3 * RNNH], sC[u + 3 * RNNH]);
            float cn = sigm(gi) * ftanh(gg);
            c[u] = cn;
            float hu = sigm(go) * ftanh(cn);
            myh[u] = hu;
            oacc = fmaf(hu, sW2r[u], oacc);
        }
    }

    for (int j = 1; j < len; j++) {
        float xj = 0.0f;
        if ((m >> j) & 1u) xj = (j == 16) ? v2.y : vrow[j];

        float a1[2 * RNNH];
#pragma unroll
        for (int q = 0; q < 5; q++) {
            float4 ai = ((const float4*)sA)[q],      ci = ((const float4*)sC)[q];
            float4 ag = ((const float4*)sA)[10 + q], cg = ((const float4*)sC)[10 + q];
            a1[4 * q + 0] = fmaf(xj, ai.x, ci.x);
            a1[4 * q + 1] = fmaf(xj, ai.y, ci.y);
            a1[4 * q + 2] = fmaf(xj, ai.z, ci.z);
            a1[4 * q + 3] = fmaf(xj, ai.w, ci.w);
            a1[RNNH + 4 * q + 0] = fmaf(xj, ag.x, cg.x);
            a1[RNNH + 4 * q + 1] = fmaf(xj, ag.y, cg.y);
            a1[RNNH + 4 * q + 2] = fmaf(xj, ag.z, cg.z);
            a1[RNNH + 4 * q + 3] = fmaf(xj, ag.w, cg.w);
        }
#pragma unroll 1
        for (int k = 0; k < RNNH; k++) {
            float hk = myh[k];
            const float4* wr = (const float4*)&sW1t[k][0];
#pragma unroll
            for (int q = 0; q < 10; q++) {
                float4 w = wr[q];
                a1[4 * q + 0] = fmaf(hk, w.x, a1[4 * q + 0]);
                a1[4 * q + 1] = fmaf(hk, w.y, a1[4 * q + 1]);
                a1[4 * q + 2] = fmaf(hk, w.z, a1[4 * q + 2]);
                a1[4 * q + 3] = fmaf(hk, w.w, a1[4 * q + 3]);
            }
        }
        float cand[RNNH];
#pragma unroll
        for (int u = 0; u < RNNH; u++) cand[u] = sigm(a1[u]) * ftanh(a1[RNNH + u]);

        float a2[2 * RNNH];
#pragma unroll
        for (int q = 0; q < 5; q++) {
            float4 af = ((const float4*)sA)[5 + q],  cf = ((const float4*)sC)[5 + q];
            float4 ao = ((const float4*)sA)[15 + q], co = ((const float4*)sC)[15 + q];
            a2[4 * q + 0] = fmaf(xj, af.x, cf.x);
            a2[4 * q + 1] = fmaf(xj, af.y, cf.y);
            a2[4 * q + 2] = fmaf(xj, af.z, cf.z);
            a2[4 * q + 3] = fmaf(xj, af.w, cf.w);
            a2[RNNH + 4 * q + 0] = fmaf(xj, ao.x, co.x);
            a2[RNNH + 4 * q + 1] = fmaf(xj, ao.y, co.y);
            a2[RNNH + 4 * q + 2] = fmaf(xj, ao.z, co.z);
            a2[RNNH + 4 * q + 3] = fmaf(xj, ao.w, co.w);
        }
#pragma unroll 1
        for (int k = 0; k < RNNH; k++) {
            float hk = myh[k];
            const float4* wr = (const float4*)&sW2t[k][0];
#pragma unroll
            for (int q = 0; q < 10; q++) {
                float4 w = wr[q];
                a2[4 * q + 0] = fmaf(hk, w.x, a2[4 * q + 0]);
                a2[4 * q + 1] = fmaf(hk, w.y, a2[4 * q + 1]);
                a2[4 * q + 2] = fmaf(hk, w.z, a2[4 * q + 2]);
                a2[4 * q + 3] = fmaf(hk, w.w, a2[4 * q + 3]);
            }
        }

        oacc = sb2o;
#pragma unroll
        for (int u = 0; u < RNNH; u++) {
            float cn = fmaf(sigm(a2[u]), c[u], cand[u]);
            c[u] = cn;
            float hu = sigm(a2[RNNH + u]) * ftanh(cn);
            myh[u] = hu;
            oacc = fmaf(hu, sW2r[u], oacc);
        }
    }

    out[row] = oacc;
}

#define STAGE_LSTM_WEIGHTS()                                                     \
    for (int i = tid; i < 4 * RNNH * RNNH; i += blockDim.x) {                    \
        int gu = i / RNNH, k = i % RNNH;                                         \
        int gate = gu / RNNH, u = gu % RNNH;                                     \
        float w = Whh[i];                                                        \
        if      (gate == 0) sW1t[k][u]        = w;                               \
        else if (gate == 2) sW1t[k][RNNH + u] = w;                               \
        else if (gate == 1) sW2t[k][u]        = w;                               \
        else                sW2t[k][RNNH + u] = w;                               \
    }                                                                            \
    if (tid < 4 * RNNH) {                                                        \
        float a = 0.0f, cc = bih[tid] + bhh[tid];                                \
        for (int k = 0; k < RNNH; k++) {                                         \
            float w = Wih[tid * RNNH + k];                                       \
            a = fmaf(rW1[k], w, a);                                              \
            cc = fmaf(rb1[k], w, cc);                                            \
        }                                                                        \
        sA[tid] = a; sC[tid] = cc;                                               \
    }                                                                            \
    if (tid < RNNH) sW2r[tid] = rW2[tid];                                        \
    if (tid == 0) sb2o = rb2[0];                                                 \
    __syncthreads();

// ---------------- Kernel 1: pair fast-path + last-block worklist processing ----------------
__global__ __launch_bounds__(256, 4) void ev_pair_scatter(
    const float* __restrict__ ev, int n,
    const float2* __restrict__ tbl2,
    float* __restrict__ vox, unsigned int* __restrict__ mask,
    float* __restrict__ outp, float2* __restrict__ vv,
    int* __restrict__ wl, unsigned int* __restrict__ counters,
    const float* __restrict__ rW1, const float* __restrict__ rb1,
    const float* __restrict__ Wih, const float* __restrict__ Whh,
    const float* __restrict__ bih, const float* __restrict__ bhh,
    const float* __restrict__ rW2, const float* __restrict__ rb2)
{
    unsigned int* wl_count     = &counters[0];
    unsigned int* finish_count = &counters[1];
    int tid = threadIdx.x;
    int p = blockIdx.x * blockDim.x + tid;
    int i0 = 2 * p;

    if (i0 < n) {
        bool have2 = (i0 + 1 < n);
        const float* e0 = ev + (size_t)i0 * 7;
        float t0 = e0[3];
        int row0 = (int)e0[0] + WW * (int)e0[1] + WW * HH * (int)e0[2]
                 + 2 * WW * HH * ((int)e0[6] * T_AGGC + (int)e0[5]);
        int pos0 = (int)e0[4] - 1;

        float t1 = 0.0f; int row1 = -1, pos1 = -1;
        if (have2) {
            const float* e1 = e0 + 7;
            t1 = e1[3];
            row1 = (int)e1[0] + WW * (int)e1[1] + WW * HH * (int)e1[2]
                 + 2 * WW * HH * ((int)e1[6] * T_AGGC + (int)e1[5]);
            pos1 = (int)e1[4] - 1;
        }

        bool done = false;
        if (have2 && row0 == row1 &&
            ((pos0 == 0 && pos1 == 16) || (pos0 == 16 && pos1 == 0))) {
            float ta = (pos0 == 0) ? t0 : t1;
            float tb = (pos0 == 0) ? t1 : t0;
            float2 la = tbl2_lerp(tbl2, ta);    // {v0, out}
            float v16 = tbl2_lerp(tbl2, tb).x;
            if (la.x != 0.0f && v16 != 0.0f) {
                outp[row0] = la.y;              // standard row: single 4B store
                done = true;
            }
        }
        if (!done) {
            {
                float val = tbl2_lerp(tbl2, t0).x;
                if (pos0 == 0)       vv[row0].x = val;
                else if (pos0 == 16) vv[row0].y = val;
                else                 vox[(size_t)row0 * M_EVC + pos0] = val;
                if (val != 0.0f) atomicOr(&mask[row0], 1u << pos0);
                unsigned idx = atomicAdd(wl_count, 1u);
                if (idx < (unsigned)ROWS) wl[idx] = row0;
            }
            if (have2) {
                float val = tbl2_lerp(tbl2, t1).x;
                if (pos1 == 0)       vv[row1].x = val;
                else if (pos1 == 16) vv[row1].y = val;
                else                 vox[(size_t)row1 * M_EVC + pos1] = val;
                if (val != 0.0f) atomicOr(&mask[row1], 1u << pos1);
                unsigned idx = atomicAdd(wl_count, 1u);
                if (idx < (unsigned)ROWS) wl[idx] = row1;
            }
        }
    }

    // ---- decoupled last-block worklist processing ----
    __shared__ __align__(16) float sW1t[RNNH][2 * RNNH];
    __shared__ __align__(16) float sW2t[RNNH][2 * RNNH];
    __shared__ __align__(16) float sA[4 * RNNH], sC[4 * RNNH];
    __shared__ float sW2r[RNNH];
    __shared__ float sb2o;
    __shared__ float sH[64 * HPAD];
    __shared__ int sIsLast;

    __threadfence();
    __syncthreads();
    if (tid == 0) {
        unsigned prior = atomicAdd(finish_count, 1u);
        sIsLast = (prior == gridDim.x - 1) ? 1 : 0;
    }
    __syncthreads();
    if (!sIsLast) return;

    __threadfence();                       // acquire: make other blocks' writes visible
    int cnt = (int)*wl_count; if (cnt > ROWS) cnt = ROWS;
    if (cnt == 0) return;

    STAGE_LSTM_WEIGHTS();

    if (tid < 64) {
        for (int e = tid; e < cnt; e += 64) {
            int row = wl[e];
            lstm_row(row, mask[row], vox, vv, sW1t, sW2t, sA, sC, sW2r, sb2o,
                     &sH[tid * HPAD], outp);
        }
    }
}

// ---------------- Fallback kernels (only if ws too small for tables) ----------------
__global__ __launch_bounds__(256) void ev_exact_scatter(
    const float* __restrict__ ev, int n,
    const float* __restrict__ W1, const float* __restrict__ b1,
    const float* __restrict__ W2, const float* __restrict__ b2,
    const float* __restrict__ W3, const float* __restrict__ b3,
    float* __restrict__ vox, unsigned int* __restrict__ mask,
    float2* __restrict__ vv)
{
    __shared__ __align__(16) float sW2[MLPH * MLPH];
    __shared__ float sW1[MLPH], sb1[MLPH], sb2[MLPH], sW3[MLPH];
    __shared__ float sb3;
    int tid = threadIdx.x;
    for (int i = tid; i < MLPH * MLPH; i += blockDim.x) sW2[i] = W2[i];
    if (tid < MLPH) { sW1[tid] = W1[tid]; sb1[tid] = b1[tid]; sb2[tid] = b2[tid]; sW3[tid] = W3[tid]; }
    if (tid == 0) sb3 = b3[0];
    __syncthreads();

    int i = blockIdx.x * blockDim.x + tid;
    if (i >= n) return;
    const float* e = ev + (size_t)i * 7;
    float t = e[3];

    float h1[MLPH];
#pragma unroll
    for (int k = 0; k < MLPH; k++) h1[k] = lrelu(fmaf(t, sW1[k], sb1[k]));
    float val = sb3;
#pragma unroll
    for (int j = 0; j < MLPH; j++) {
        float a = sb2[j];
        const float4* wr = (const float4*)&sW2[j * MLPH];
#pragma unroll
        for (int k4 = 0; k4 < MLPH / 4; k4++) {
            float4 w = wr[k4];
            a = fmaf(h1[k4 * 4 + 0], w.x, a);
            a = fmaf(h1[k4 * 4 + 1], w.y, a);
            a = fmaf(h1[k4 * 4 + 2], w.z, a);
            a = fmaf(h1[k4 * 4 + 3], w.w, a);
        }
        val = fmaf(lrelu(a), sW3[j], val);
    }

    int row = (int)e[0] + WW * (int)e[1] + WW * HH * (int)e[2]
            + 2 * WW * HH * ((int)e[6] * T_AGGC + (int)e[5]);
    int pos = (int)e[4] - 1;
    if (pos == 0)       vv[row].x = val;
    else if (pos == 16) vv[row].y = val;
    else                vox[(size_t)row * M_EVC + pos] = val;
    if (val != 0.0f) atomicOr(&mask[row], 1u << pos);
}

__global__ __launch_bounds__(256) void row_out_scan(
    const unsigned int* __restrict__ mask,
    const float* __restrict__ vox, const float2* __restrict__ vv,
    const float* __restrict__ rW1, const float* __restrict__ rb1,
    const float* __restrict__ Wih, const float* __restrict__ Whh,
    const float* __restrict__ bih, const float* __restrict__ bhh,
    const float* __restrict__ rW2, const float* __restrict__ rb2,
    float* __restrict__ out)
{
    __shared__ __align__(16) float sW1t[RNNH][2 * RNNH];
    __shared__ __align__(16) float sW2t[RNNH][2 * RNNH];
    __shared__ __align__(16) float sA[4 * RNNH], sC[4 * RNNH];
    __shared__ float sW2r[RNNH];
    __shared__ float sb2o;
    __shared__ float sH[256 * HPAD];

    int tid = threadIdx.x;
    int g = blockIdx.x * blockDim.x + tid;
    bool inb = (g < ROWS / 4);

    uint4 m4 = make_uint4(0u, 0u, 0u, 0u);
    if (inb) m4 = ((const uint4*)mask)[g];
    bool fb0 = m4.x != 0u, fb1 = m4.y != 0u, fb2 = m4.z != 0u, fb3 = m4.w != 0u;
    bool anyfb = fb0 | fb1 | fb2 | fb3;

    if (!__syncthreads_or(anyfb ? 1 : 0)) return;

    STAGE_LSTM_WEIGHTS();

    if (!anyfb) return;
    float* myh = &sH[tid * HPAD];
    if (fb0) lstm_row(4 * g + 0, m4.x, vox, vv, sW1t, sW2t, sA, sC, sW2r, sb2o, myh, out);
    if (fb1) lstm_row(4 * g + 1, m4.y, vox, vv, sW1t, sW2t, sA, sC, sW2r, sb2o, myh, out);
    if (fb2) lstm_row(4 * g + 2, m4.z, vox, vv, sW1t, sW2t, sA, sC, sW2r, sb2o, myh, out);
    if (fb3) lstm_row(4 * g + 3, m4.w, vox, vv, sW1t, sW2t, sA, sC, sW2r, sb2o, myh, out);
}

extern "C" void kernel_launch(void* const* d_in, const int* in_sizes, int n_in,
                              void* d_out, int out_size, void* d_ws, size_t ws_size,
                              hipStream_t stream) {
    const float* ev     = (const float*)d_in[0];
    const float* mlp_W1 = (const float*)d_in[1];
    const float* mlp_b1 = (const float*)d_in[2];
    const float* mlp_W2 = (const float*)d_in[3];
    const float* mlp_b2 = (const float*)d_in[4];
    const float* mlp_W3 = (const float*)d_in[5];
    const float* mlp_b3 = (const float*)d_in[6];
    const float* rnn_W1 = (const float*)d_in[7];
    const float* rnn_b1 = (const float*)d_in[8];
    const float* W_ih   = (const float*)d_in[9];
    const float* W_hh   = (const float*)d_in[10];
    const float* b_ih   = (const float*)d_in[11];
    const float* b_hh   = (const float*)d_in[12];
    const float* rnn_W2 = (const float*)d_in[13];
    const float* rnn_b2 = (const float*)d_in[14];

    int n = in_sizes[0] / 7;
    float* outp = (float*)d_out;

    unsigned char* ws = (unsigned char*)d_ws;
    size_t off = 0;
    unsigned int* mask = (unsigned int*)(ws + off); off += (size_t)ROWS * 4;
    float*        vox  = (float*)(ws + off);        off += (size_t)ROWS * M_EVC * 4;
    float2* tbl2   = (float2*)(ws + off); off += (size_t)TBL * 8;
    float2* vv     = (float2*)(ws + off); off += (size_t)ROWS * 8;
    int* wl        = (int*)(ws + off);   off += (size_t)ROWS * 4;
    unsigned int* counters = (unsigned int*)(ws + off); off += 16;
    size_t all_need = off;

    int use_table = (ws_size >= all_need) ? 1 : 0;

    int blk = 256;
    if (use_table) {
        build_tables<<<1024, blk, 0, stream>>>(mlp_W1, mlp_b1, mlp_W2, mlp_b2,
                                               mlp_W3, mlp_b3,
                                               rnn_W1, rnn_b1, W_ih, W_hh,
                                               b_ih, b_hh, rnn_W2, rnn_b2,
                                               tbl2, mask, outp, counters);
        int npairs = (n + 1) / 2;
        int grid1 = (npairs + blk - 1) / blk;
        ev_pair_scatter<<<grid1, blk, 0, stream>>>(ev, n, tbl2,
                                                   vox, mask, outp, vv, wl, counters,
                                                   rnn_W1, rnn_b1, W_ih, W_hh,
                                                   b_ih, b_hh, rnn_W2, rnn_b2);
    } else {
        hipMemsetAsync(mask, 0, (size_t)ROWS * 4, stream);
        hipMemsetAsync(outp, 0, (size_t)ROWS * 4, stream);
        int grid1 = (n + blk - 1) / blk;
        ev_exact_scatter<<<grid1, blk, 0, stream>>>(ev, n, mlp_W1, mlp_b1, mlp_W2, mlp_b2,
                                                    mlp_W3, mlp_b3, vox, mask, vv);
        int grid2 = (ROWS / 4 + blk - 1) / blk;
        row_out_scan<<<grid2, blk, 0, stream>>>(mask, vox, vv,
                                                rnn_W1, rnn_b1, W_ih, W_hh,
                                                b_ih, b_hh, rnn_W2, rnn_b2, outp);
    }
}

// Round 17
// 43.904 us; speedup vs baseline: 8.3935x; 8.3935x over previous
//
#include <hip/hip_runtime.h>
#include <math.h>

#define HH 180
#define WW 240
#define T_AGGC 3
#define NBC 4
#define BBC (NBC * T_AGGC)          // 12
#define M_EVC 32
#define ROWS (BBC * 2 * HH * WW)    // 1,036,800
#define MLPH 20
#define RNNH 20
#define LRELU_SLOPE 0.1f
#define HPAD 21
#define TBL 8192                    // table entries over t in [-1,1]
#define TE 64                       // table entries per block (build kernel)

__device__ __forceinline__ float lrelu(float x) { return x > 0.0f ? x : LRELU_SLOPE * x; }
__device__ __forceinline__ float sigm(float x)  { return 1.0f / (1.0f + __expf(-x)); }
__device__ __forceinline__ float ftanh(float x) { return 1.0f - 2.0f / (__expf(2.0f * x) + 1.0f); }

// fused {mlp, g} table lookup
__device__ __forceinline__ float2 tbl2_lerp(const float2* __restrict__ tbl, float t) {
    float x = (t + 1.0f) * (0.5f * (TBL - 1));
    x = fminf(fmaxf(x, 0.0f), (float)(TBL - 1));
    int idx = (int)x; if (idx > TBL - 2) idx = TBL - 2;
    float frac = x - (float)idx;
    float2 a = tbl[idx], b = tbl[idx + 1];
    return make_float2(fmaf(frac, b.x - a.x, a.x), fmaf(frac, b.y - a.y, a.y));
}

// ---------------- Table builder (4 threads/entry) + fused zeroing ----------------
__global__ __launch_bounds__(256) void build_tables(
    const float* __restrict__ W1, const float* __restrict__ b1,
    const float* __restrict__ W2, const float* __restrict__ b2,
    const float* __restrict__ W3, const float* __restrict__ b3,
    const float* __restrict__ rW1, const float* __restrict__ rb1,
    const float* __restrict__ Wih, const float* __restrict__ Whh,
    const float* __restrict__ bih, const float* __restrict__ bhh,
    const float* __restrict__ rW2, const float* __restrict__ rb2,
    float2* __restrict__ tbl2,
    unsigned int* __restrict__ mask_z, float* __restrict__ out_z,
    unsigned int* __restrict__ wl_count)
{
    int tid = threadIdx.x;
    for (int gidx = blockIdx.x * blockDim.x + tid; gidx < ROWS / 4; gidx += gridDim.x * blockDim.x) {
        uint4 z = make_uint4(0u, 0u, 0u, 0u);
        ((uint4*)mask_z)[gidx] = z;
        ((uint4*)out_z)[gidx]  = z;
    }
    if (blockIdx.x == 0 && tid == 0) *wl_count = 0u;
    if (blockIdx.x * TE >= TBL) return;

    __shared__ __align__(16) float sW2m[MLPH * MLPH];
    __shared__ float sW1m[MLPH], sb1m[MLPH], sb2m[MLPH], sW3m[MLPH];
    __shared__ __align__(16) float sW[4 * RNNH * RNNH];   // Whh row-major
    __shared__ __align__(16) float sA[4 * RNNH], sC[4 * RNNH];
    __shared__ float sW2r[RNNH];
    __shared__ float sConst[2];                           // [0]=b3, [1]=rb2
    __shared__ float sH0[TE][HPAD];
    __shared__ float sRed[TE][4];

    for (int i = tid; i < MLPH * MLPH; i += blockDim.x) sW2m[i] = W2[i];
    for (int i = tid; i < 4 * RNNH * RNNH; i += blockDim.x) sW[i] = Whh[i];
    if (tid < MLPH) { sW1m[tid] = W1[tid]; sb1m[tid] = b1[tid]; sb2m[tid] = b2[tid]; sW3m[tid] = W3[tid]; }
    if (tid < 4 * RNNH) {
        float a = 0.0f, cc = bih[tid] + bhh[tid];
        for (int k = 0; k < RNNH; k++) {
            float w = Wih[tid * RNNH + k];
            a = fmaf(rW1[k], w, a);
            cc = fmaf(rb1[k], w, cc);
        }
        sA[tid] = a; sC[tid] = cc;
    }
    if (tid < RNNH) sW2r[tid] = rW2[tid];
    if (tid == 0) { sConst[0] = b3[0]; sConst[1] = rb2[0]; }
    __syncthreads();

    int e    = tid & (TE - 1);
    int part = tid >> 6;
    int ubase = part * 5;
    int i = blockIdx.x * TE + e;
    float t = -1.0f + (2.0f / (TBL - 1)) * (float)i;

    float h1[MLPH];
#pragma unroll
    for (int k = 0; k < MLPH; k++) h1[k] = lrelu(fmaf(t, sW1m[k], sb1m[k]));

    float vpart = 0.0f;
#pragma unroll
    for (int r = 0; r < 5; r++) {
        int j = ubase + r;
        float a = sb2m[j];
        const float* wr = &sW2m[j * MLPH];
#pragma unroll
        for (int k = 0; k < MLPH; k++) a = fmaf(h1[k], wr[k], a);
        vpart = fmaf(lrelu(a), sW3m[j], vpart);
    }
    sRed[e][part] = vpart;
    __syncthreads();
    float val = sRed[e][0] + sRed[e][1] + sRed[e][2] + sRed[e][3] + sConst[0];

    float c1loc[5];
#pragma unroll
    for (int r = 0; r < 5; r++) {
        int u = ubase + r;
        float gi = fmaf(val, sA[u],            sC[u]);
        float gg = fmaf(val, sA[u + 2 * RNNH], sC[u + 2 * RNNH]);
        float go = fmaf(val, sA[u + 3 * RNNH], sC[u + 3 * RNNH]);
        float cn = sigm(gi) * ftanh(gg);
        c1loc[r] = cn;
        sH0[e][u] = sigm(go) * ftanh(cn);
    }
    __syncthreads();

    float opart = 0.0f;
#pragma unroll
    for (int r = 0; r < 5; r++) {
        int u = ubase + r;
        float gi = sC[u], gf = sC[u + RNNH], gg = sC[u + 2 * RNNH], go = sC[u + 3 * RNNH];
        const float* wi = &sW[u * RNNH];
        const float* wf = &sW[(u + RNNH) * RNNH];
        const float* wg = &sW[(u + 2 * RNNH) * RNNH];
        const float* wo = &sW[(u + 3 * RNNH) * RNNH];
#pragma unroll
        for (int k = 0; k < RNNH; k++) {
            float hk = sH0[e][k];
            gi = fmaf(hk, wi[k], gi);
            gf = fmaf(hk, wf[k], gf);
            gg = fmaf(hk, wg[k], gg);
            go = fmaf(hk, wo[k], go);
        }
        float c2 = fmaf(sigm(gf), c1loc[r], sigm(gi) * ftanh(gg));
        opart = fmaf(sigm(go) * ftanh(c2), sW2r[u], opart);
    }
    __syncthreads();
    sRed[e][part] = opart;
    __syncthreads();
    if (part == 0)
        tbl2[i] = make_float2(val, sRed[e][0] + sRed[e][1] + sRed[e][2] + sRed[e][3] + sConst[1]);
}

// ---------------- Kernel 1: pair fast-path; anomalies -> worklist ----------------
__global__ __launch_bounds__(256) void ev_pair_scatter(
    const float* __restrict__ ev, int n,
    const float2* __restrict__ tbl2,
    float* __restrict__ vox, unsigned int* __restrict__ mask,
    float* __restrict__ outp, float2* __restrict__ vv,
    int* __restrict__ wl, unsigned int* __restrict__ wl_count)
{
    int p = blockIdx.x * blockDim.x + threadIdx.x;
    int i0 = 2 * p;
    if (i0 >= n) return;
    bool have2 = (i0 + 1 < n);

    const float* e0 = ev + (size_t)i0 * 7;
    float t0 = e0[3];
    int row0 = (int)e0[0] + WW * (int)e0[1] + WW * HH * (int)e0[2]
             + 2 * WW * HH * ((int)e0[6] * T_AGGC + (int)e0[5]);
    int pos0 = (int)e0[4] - 1;

    float t1 = 0.0f; int row1 = -1, pos1 = -1;
    if (have2) {
        const float* e1 = e0 + 7;
        t1 = e1[3];
        row1 = (int)e1[0] + WW * (int)e1[1] + WW * HH * (int)e1[2]
             + 2 * WW * HH * ((int)e1[6] * T_AGGC + (int)e1[5]);
        pos1 = (int)e1[4] - 1;
    }

    if (have2 && row0 == row1 &&
        ((pos0 == 0 && pos1 == 16) || (pos0 == 16 && pos1 == 0))) {
        float ta = (pos0 == 0) ? t0 : t1;
        float tb = (pos0 == 0) ? t1 : t0;
        float2 la = tbl2_lerp(tbl2, ta);       // {v0, out}
        float v16 = tbl2_lerp(tbl2, tb).x;
        if (la.x != 0.0f && v16 != 0.0f) {
            outp[row0] = la.y;                 // standard row: single 4B store
            return;
        }
        // degenerate: fall through to general path
    }

    // general path, per event: scatter + mask + worklist push
    {
        float val = tbl2_lerp(tbl2, t0).x;
        if (pos0 == 0)       vv[row0].x = val;
        else if (pos0 == 16) vv[row0].y = val;
        else                 vox[(size_t)row0 * M_EVC + pos0] = val;
        if (val != 0.0f) atomicOr(&mask[row0], 1u << pos0);
        unsigned idx = atomicAdd(wl_count, 1u);
        if (idx < (unsigned)ROWS) wl[idx] = row0;
    }
    if (have2) {
        float val = tbl2_lerp(tbl2, t1).x;
        if (pos1 == 0)       vv[row1].x = val;
        else if (pos1 == 16) vv[row1].y = val;
        else                 vox[(size_t)row1 * M_EVC + pos1] = val;
        if (val != 0.0f) atomicOr(&mask[row1], 1u << pos1);
        unsigned idx = atomicAdd(wl_count, 1u);
        if (idx < (unsigned)ROWS) wl[idx] = row1;
    }
}

// ---------------- shared LSTM fallback body ----------------
__device__ void lstm_row(
    int row, unsigned m,
    const float* __restrict__ vox, const float2* __restrict__ vv,
    const float (*sW1t)[2 * RNNH], const float (*sW2t)[2 * RNNH],
    const float* sA, const float* sC, const float* sW2r, float sb2o,
    float* myh, float* __restrict__ out)
{
    const float* vrow = vox + (size_t)row * M_EVC;
    float2 v2 = vv[row];

    float s = 0.0f;
    {
        unsigned mm = m;
        while (mm) {
            int j = __ffs(mm) - 1; mm &= mm - 1;
            float v;
            if (j == 0)       v = v2.x;
            else if (j == 16) v = v2.y;
            else              v = vrow[j];
            s += v;
        }
    }
    if (s == 0.0f) { out[row] = 0.0f; return; }

    int len = __popc(m);
    float c[RNNH];
    float oacc;

    {
        float x0 = (m & 1u) ? v2.x : 0.0f;
        oacc = sb2o;
#pragma unroll
        for (int u = 0; u < RNNH; u++) {
            float gi = fmaf(x0, sA[u],            sC[u]);
            float gg = fmaf(x0, sA[u + 2 * RNNH], sC[u + 2 * RNNH]);
            float go = fmaf(x0, sA[u + 3 * RNNH], sC[u + 3 * RNNH]);
            float cn = sigm(gi) * ftanh(gg);
            c[u] = cn;
            float hu = sigm(go) * ftanh(cn);
            myh[u] = hu;
            oacc = fmaf(hu, sW2r[u], oacc);
        }
    }

    for (int j = 1; j < len; j++) {
        float xj = 0.0f;
        if ((m >> j) & 1u) xj = (j == 16) ? v2.y : vrow[j];

        float a1[2 * RNNH];
#pragma unroll
        for (int q = 0; q < 5; q++) {
            float4 ai = ((const float4*)sA)[q],      ci = ((const float4*)sC)[q];
            float4 ag = ((const float4*)sA)[10 + q], cg = ((const float4*)sC)[10 + q];
            a1[4 * q + 0] = fmaf(xj, ai.x, ci.x);
            a1[4 * q + 1] = fmaf(xj, ai.y, ci.y);
            a1[4 * q + 2] = fmaf(xj, ai.z, ci.z);
            a1[4 * q + 3] = fmaf(xj, ai.w, ci.w);
            a1[RNNH + 4 * q + 0] = fmaf(xj, ag.x, cg.x);
            a1[RNNH + 4 * q + 1] = fmaf(xj, ag.y, cg.y);
            a1[RNNH + 4 * q + 2] = fmaf(xj, ag.z, cg.z);
            a1[RNNH + 4 * q + 3] = fmaf(xj, ag.w, cg.w);
        }
#pragma unroll 1
        for (int k = 0; k < RNNH; k++) {
            float hk = myh[k];
            const float4* wr = (const float4*)&sW1t[k][0];
#pragma unroll
            for (int q = 0; q < 10; q++) {
                float4 w = wr[q];
                a1[4 * q + 0] = fmaf(hk, w.x, a1[4 * q + 0]);
                a1[4 * q + 1] = fmaf(hk, w.y, a1[4 * q + 1]);
                a1[4 * q + 2] = fmaf(hk, w.z, a1[4 * q + 2]);
                a1[4 * q + 3] = fmaf(hk, w.w, a1[4 * q + 3]);
            }
        }
        float cand[RNNH];
#pragma unroll
        for (int u = 0; u < RNNH; u++) cand[u] = sigm(a1[u]) * ftanh(a1[RNNH + u]);

        float a2[2 * RNNH];
#pragma unroll
        for (int q = 0; q < 5; q++) {
            float4 af = ((const float4*)sA)[5 + q],  cf = ((const float4*)sC)[5 + q];
            float4 ao = ((const float4*)sA)[15 + q], co = ((const float4*)sC)[15 + q];
            a2[4 * q + 0] = fmaf(xj, af.x, cf.x);
            a2[4 * q + 1] = fmaf(xj, af.y, cf.y);
            a2[4 * q + 2] = fmaf(xj, af.z, cf.z);
            a2[4 * q + 3] = fmaf(xj, af.w, cf.w);
            a2[RNNH + 4 * q + 0] = fmaf(xj, ao.x, co.x);
            a2[RNNH + 4 * q + 1] = fmaf(xj, ao.y, co.y);
            a2[RNNH + 4 * q + 2] = fmaf(xj, ao.z, co.z);
            a2[RNNH + 4 * q + 3] = fmaf(xj, ao.w, co.w);
        }
#pragma unroll 1
        for (int k = 0; k < RNNH; k++) {
            float hk = myh[k];
            const float4* wr = (const float4*)&sW2t[k][0];
#pragma unroll
            for (int q = 0; q < 10; q++) {
                float4 w = wr[q];
                a2[4 * q + 0] = fmaf(hk, w.x, a2[4 * q + 0]);
                a2[4 * q + 1] = fmaf(hk, w.y, a2[4 * q + 1]);
                a2[4 * q + 2] = fmaf(hk, w.z, a2[4 * q + 2]);
                a2[4 * q + 3] = fmaf(hk, w.w, a2[4 * q + 3]);
            }
        }

        oacc = sb2o;
#pragma unroll
        for (int u = 0; u < RNNH; u++) {
            float cn = fmaf(sigm(a2[u]), c[u], cand[u]);
            c[u] = cn;
            float hu = sigm(a2[RNNH + u]) * ftanh(cn);
            myh[u] = hu;
            oacc = fmaf(hu, sW2r[u], oacc);
        }
    }

    out[row] = oacc;
}

#define STAGE_LSTM_WEIGHTS()                                                     \
    for (int i = tid; i < 4 * RNNH * RNNH; i += blockDim.x) {                    \
        int gu = i / RNNH, k = i % RNNH;                                         \
        int gate = gu / RNNH, u = gu % RNNH;                                     \
        float w = Whh[i];                                                        \
        if      (gate == 0) sW1t[k][u]        = w;                               \
        else if (gate == 2) sW1t[k][RNNH + u] = w;                               \
        else if (gate == 1) sW2t[k][u]        = w;                               \
        else                sW2t[k][RNNH + u] = w;                               \
    }                                                                            \
    if (tid < 4 * RNNH) {                                                        \
        float a = 0.0f, cc = bih[tid] + bhh[tid];                                \
        for (int k = 0; k < RNNH; k++) {                                         \
            float w = Wih[tid * RNNH + k];                                       \
            a = fmaf(rW1[k], w, a);                                              \
            cc = fmaf(rb1[k], w, cc);                                            \
        }                                                                        \
        sA[tid] = a; sC[tid] = cc;                                               \
    }                                                                            \
    if (tid < RNNH) sW2r[tid] = rW2[tid];                                        \
    if (tid == 0) sb2o = rb2[0];                                                 \
    __syncthreads();

// ---------------- Kernel 2: process only worklisted rows (tiny) ----------------
__global__ __launch_bounds__(256) void row_fix(
    const unsigned int* __restrict__ wl_count, const int* __restrict__ wl,
    const unsigned int* __restrict__ mask,
    const float* __restrict__ vox, const float2* __restrict__ vv,
    const float* __restrict__ rW1, const float* __restrict__ rb1,
    const float* __restrict__ Wih, const float* __restrict__ Whh,
    const float* __restrict__ bih, const float* __restrict__ bhh,
    const float* __restrict__ rW2, const float* __restrict__ rb2,
    float* __restrict__ out)
{
    int cnt = (int)min(*wl_count, (unsigned)ROWS);
    if (cnt == 0) return;

    __shared__ __align__(16) float sW1t[RNNH][2 * RNNH];
    __shared__ __align__(16) float sW2t[RNNH][2 * RNNH];
    __shared__ __align__(16) float sA[4 * RNNH], sC[4 * RNNH];
    __shared__ float sW2r[RNNH];
    __shared__ float sb2o;
    __shared__ float sH[256 * HPAD];
    int tid = threadIdx.x;

    STAGE_LSTM_WEIGHTS();

    for (int e = blockIdx.x * blockDim.x + tid; e < cnt; e += gridDim.x * blockDim.x) {
        int row = wl[e];
        lstm_row(row, mask[row], vox, vv, sW1t, sW2t, sA, sC, sW2r, sb2o,
                 &sH[tid * HPAD], out);
    }
}

// ---------------- Fallback kernels (only if ws too small for tables) ----------------
__global__ __launch_bounds__(256) void ev_exact_scatter(
    const float* __restrict__ ev, int n,
    const float* __restrict__ W1, const float* __restrict__ b1,
    const float* __restrict__ W2, const float* __restrict__ b2,
    const float* __restrict__ W3, const float* __restrict__ b3,
    float* __restrict__ vox, unsigned int* __restrict__ mask,
    float2* __restrict__ vv)
{
    __shared__ __align__(16) float sW2[MLPH * MLPH];
    __shared__ float sW1[MLPH], sb1[MLPH], sb2[MLPH], sW3[MLPH];
    __shared__ float sb3;
    int tid = threadIdx.x;
    for (int i = tid; i < MLPH * MLPH; i += blockDim.x) sW2[i] = W2[i];
    if (tid < MLPH) { sW1[tid] = W1[tid]; sb1[tid] = b1[tid]; sb2[tid] = b2[tid]; sW3[tid] = W3[tid]; }
    if (tid == 0) sb3 = b3[0];
    __syncthreads();

    int i = blockIdx.x * blockDim.x + tid;
    if (i >= n) return;
    const float* e = ev + (size_t)i * 7;
    float t = e[3];

    float h1[MLPH];
#pragma unroll
    for (int k = 0; k < MLPH; k++) h1[k] = lrelu(fmaf(t, sW1[k], sb1[k]));
    float val = sb3;
#pragma unroll
    for (int j = 0; j < MLPH; j++) {
        float a = sb2[j];
        const float4* wr = (const float4*)&sW2[j * MLPH];
#pragma unroll
        for (int k4 = 0; k4 < MLPH / 4; k4++) {
            float4 w = wr[k4];
            a = fmaf(h1[k4 * 4 + 0], w.x, a);
            a = fmaf(h1[k4 * 4 + 1], w.y, a);
            a = fmaf(h1[k4 * 4 + 2], w.z, a);
            a = fmaf(h1[k4 * 4 + 3], w.w, a);
        }
        val = fmaf(lrelu(a), sW3[j], val);
    }

    int row = (int)e[0] + WW * (int)e[1] + WW * HH * (int)e[2]
            + 2 * WW * HH * ((int)e[6] * T_AGGC + (int)e[5]);
    int pos = (int)e[4] - 1;
    if (pos == 0)       vv[row].x = val;
    else if (pos == 16) vv[row].y = val;
    else                vox[(size_t)row * M_EVC + pos] = val;
    if (val != 0.0f) atomicOr(&mask[row], 1u << pos);
}

__global__ __launch_bounds__(256) void row_out_scan(
    const unsigned int* __restrict__ mask,
    const float* __restrict__ vox, const float2* __restrict__ vv,
    const float* __restrict__ rW1, const float* __restrict__ rb1,
    const float* __restrict__ Wih, const float* __restrict__ Whh,
    const float* __restrict__ bih, const float* __restrict__ bhh,
    const float* __restrict__ rW2, const float* __restrict__ rb2,
    float* __restrict__ out)
{
    __shared__ __align__(16) float sW1t[RNNH][2 * RNNH];
    __shared__ __align__(16) float sW2t[RNNH][2 * RNNH];
    __shared__ __align__(16) float sA[4 * RNNH], sC[4 * RNNH];
    __shared__ float sW2r[RNNH];
    __shared__ float sb2o;
    __shared__ float sH[256 * HPAD];

    int tid = threadIdx.x;
    int g = blockIdx.x * blockDim.x + tid;
    bool inb = (g < ROWS / 4);

    uint4 m4 = make_uint4(0u, 0u, 0u, 0u);
    if (inb) m4 = ((const uint4*)mask)[g];
    bool fb0 = m4.x != 0u, fb1 = m4.y != 0u, fb2 = m4.z != 0u, fb3 = m4.w != 0u;
    bool anyfb = fb0 | fb1 | fb2 | fb3;

    if (!__syncthreads_or(anyfb ? 1 : 0)) return;

    STAGE_LSTM_WEIGHTS();

    if (!anyfb) return;
    float* myh = &sH[tid * HPAD];
    if (fb0) lstm_row(4 * g + 0, m4.x, vox, vv, sW1t, sW2t, sA, sC, sW2r, sb2o, myh, out);
    if (fb1) lstm_row(4 * g + 1, m4.y, vox, vv, sW1t, sW2t, sA, sC, sW2r, sb2o, myh, out);
    if (fb2) lstm_row(4 * g + 2, m4.z, vox, vv, sW1t, sW2t, sA, sC, sW2r, sb2o, myh, out);
    if (fb3) lstm_row(4 * g + 3, m4.w, vox, vv, sW1t, sW2t, sA, sC, sW2r, sb2o, myh, out);
}

extern "C" void kernel_launch(void* const* d_in, const int* in_sizes, int n_in,
                              void* d_out, int out_size, void* d_ws, size_t ws_size,
                              hipStream_t stream) {
    const float* ev     = (const float*)d_in[0];
    const float* mlp_W1 = (const float*)d_in[1];
    const float* mlp_b1 = (const float*)d_in[2];
    const float* mlp_W2 = (const float*)d_in[3];
    const float* mlp_b2 = (const float*)d_in[4];
    const float* mlp_W3 = (const float*)d_in[5];
    const float* mlp_b3 = (const float*)d_in[6];
    const float* rnn_W1 = (const float*)d_in[7];
    const float* rnn_b1 = (const float*)d_in[8];
    const float* W_ih   = (const float*)d_in[9];
    const float* W_hh   = (const float*)d_in[10];
    const float* b_ih   = (const float*)d_in[11];
    const float* b_hh   = (const float*)d_in[12];
    const float* rnn_W2 = (const float*)d_in[13];
    const float* rnn_b2 = (const float*)d_in[14];

    int n = in_sizes[0] / 7;
    float* outp = (float*)d_out;

    unsigned char* ws = (unsigned char*)d_ws;
    size_t off = 0;
    unsigned int* mask = (unsigned int*)(ws + off); off += (size_t)ROWS * 4;
    float*        vox  = (float*)(ws + off);        off += (size_t)ROWS * M_EVC * 4;
    float2* tbl2   = (float2*)(ws + off); off += (size_t)TBL * 8;
    float2* vv     = (float2*)(ws + off); off += (size_t)ROWS * 8;
    int* wl        = (int*)(ws + off);   off += (size_t)ROWS * 4;
    unsigned int* wl_count = (unsigned int*)(ws + off); off += 16;
    size_t all_need = off;

    int use_table = (ws_size >= all_need) ? 1 : 0;

    int blk = 256;
    if (use_table) {
        build_tables<<<1024, blk, 0, stream>>>(mlp_W1, mlp_b1, mlp_W2, mlp_b2,
                                               mlp_W3, mlp_b3,
                                               rnn_W1, rnn_b1, W_ih, W_hh,
                                               b_ih, b_hh, rnn_W2, rnn_b2,
                                               tbl2, mask, outp, wl_count);
        int npairs = (n + 1) / 2;
        int grid1 = (npairs + blk - 1) / blk;
        ev_pair_scatter<<<grid1, blk, 0, stream>>>(ev, n, tbl2,
                                                   vox, mask, outp, vv, wl, wl_count);
        row_fix<<<8, blk, 0, stream>>>(wl_count, wl, mask, vox, vv,
                                       rnn_W1, rnn_b1, W_ih, W_hh,
                                       b_ih, b_hh, rnn_W2, rnn_b2, outp);
    } else {
        hipMemsetAsync(mask, 0, (size_t)ROWS * 4, stream);
        hipMemsetAsync(outp, 0, (size_t)ROWS * 4, stream);
        int grid1 = (n + blk - 1) / blk;
        ev_exact_scatter<<<grid1, blk, 0, stream>>>(ev, n, mlp_W1, mlp_b1, mlp_W2, mlp_b2,
                                                    mlp_W3, mlp_b3, vox, mask, vv);
        int grid2 = (ROWS / 4 + blk - 1) / blk;
        row_out_scan<<<grid2, blk, 0, stream>>>(mask, vox, vv,
                                                rnn_W1, rnn_b1, W_ih, W_hh,
                                                b_ih, b_hh, rnn_W2, rnn_b2, outp);
    }
}